// Round 1
// baseline (13012.944 us; speedup 1.0000x reference)
//
#include <hip/hip_runtime.h>
#include <math.h>

#define BB 128
#define IMG 64
#define DD 1024
#define HID 2048
#define BD (BB*DD)
#define BLK 256

#define DT0 0.1f
#define TOL_ 0.01f
#define MIN_DT_ 0.1f
#define MAX_DELTA_T_ 20.0f
#define REL_TOL_ 1e-3f
#define LN_EPS_ 1e-3f

// RKF56 stage coefficients (a_ij), row = stage-1
__constant__ float RKA[6][5] = {
  {0.f,0.f,0.f,0.f,0.f},
  {0.25f,0.f,0.f,0.f,0.f},
  {(float)(3.0/32.0),(float)(9.0/32.0),0.f,0.f,0.f},
  {(float)(1932.0/2197.0),(float)(-7200.0/2197.0),(float)(7296.0/2197.0),0.f,0.f},
  {(float)(439.0/216.0),-8.0f,(float)(3680.0/513.0),(float)(-845.0/4104.0),0.f},
  {(float)(-8.0/27.0),2.0f,(float)(-3544.0/2565.0),(float)(1859.0/4104.0),(float)(-11.0/40.0)}
};

// ---------------- maxpool 2x2 + layernorm + state init ----------------
__global__ void pool_ln(const float* __restrict__ x, const float* __restrict__ g,
                        const float* __restrict__ bb, float* __restrict__ xs,
                        float* __restrict__ scal, int* __restrict__ flags,
                        float* __restrict__ prevE){
  __shared__ float p[DD];
  __shared__ float red[BLK];
  int b = blockIdx.x, t = threadIdx.x;
  const float* xb = x + b*IMG*IMG;
  for (int idx=t; idx<DD; idx+=BLK){
    int r = idx>>5, c = idx&31;
    const float* base = xb + (r*2)*IMG + c*2;
    p[idx] = fmaxf(fmaxf(base[0], base[1]), fmaxf(base[IMG], base[IMG+1]));
  }
  __syncthreads();
  float s=0.f;
  for (int idx=t; idx<DD; idx+=BLK) s += p[idx];
  red[t]=s; __syncthreads();
  for (int st=BLK/2; st>0; st>>=1){ if (t<st) red[t]+=red[t+st]; __syncthreads(); }
  float mean = red[0]/(float)DD; __syncthreads();
  float v=0.f;
  for (int idx=t; idx<DD; idx+=BLK){ float d=p[idx]-mean; v+=d*d; }
  red[t]=v; __syncthreads();
  for (int st=BLK/2; st>0; st>>=1){ if (t<st) red[t]+=red[t+st]; __syncthreads(); }
  float var = red[0]/(float)DD;
  float inv = 1.0f/sqrtf(var + LN_EPS_);
  for (int idx=t; idx<DD; idx+=BLK)
    xs[b*DD+idx] = (p[idx]-mean)*inv*g[idx] + bb[idx];
  if (b==0){
    if (t==0){ scal[0]=DT0; scal[1]=0.f; flags[0]=0; flags[1]=0; }
    if (t<BB) prevE[t]=0.f;
  }
}

// ---------------- evaluation point: x_eval -> z=G(x_eval), s=dG/dx ----------------
__global__ void eval_point(const float* __restrict__ xs, const float* __restrict__ kbuf,
                           float* __restrict__ z, float* __restrict__ sg,
                           const float* __restrict__ scal, const int* __restrict__ flags,
                           int stage, unsigned* err_bits, unsigned* rel_bits){
  if (flags[0]) return;
  int idx = blockIdx.x*BLK + threadIdx.x;
  if (stage==1 && idx==0){ *err_bits=0u; *rel_bits=0u; }
  float dt = scal[0];
  float acc = 0.f;
  for (int m=0; m<stage-1; ++m) acc += RKA[stage-1][m]*kbuf[m*BD+idx];
  float xe = xs[idx] + dt*acc;
  int ii = (int)xe;                // trunc toward zero == astype(int32)
  bool odd = (ii & 1) != 0;        // matches jnp floor-mod parity
  z[idx]  = odd ? (1.0f - xe) : xe;
  sg[idx] = odd ? -1.0f : 1.0f;
}

// ---------------- forward matmul: pre = A@W1 + b1 ----------------
// MODE 0: out = (pre>0) ? W2[j] : 0    (coef for backward)
// MODE 1: out = relu(pre)*W2[j]        (energy partials)
template<int MODE>
__global__ void fwd_mm(const float* __restrict__ A, const float* __restrict__ W1,
                       const float* __restrict__ b1, const float* __restrict__ W2,
                       float* __restrict__ out, const int* __restrict__ flags,
                       int need_upd){
  if (flags[0]) return;
  if (need_upd && !flags[1]) return;
  __shared__ float As[32][33];
  __shared__ float Bs[32][68];
  int j0 = blockIdx.x * 64;
  int b0 = blockIdx.y * 32;
  int t = threadIdx.x;
  int tn = t & 15, tm = t >> 4;
  float acc[2][4] = {{0.f,0.f,0.f,0.f},{0.f,0.f,0.f,0.f}};
  for (int k0 = 0; k0 < DD; k0 += 32){
    #pragma unroll
    for (int q=0; q<4; ++q){
      int e = t + 256*q;
      int r = e >> 5, c = e & 31;
      As[r][c] = A[(b0+r)*DD + k0 + c];
    }
    #pragma unroll
    for (int q=0; q<8; ++q){
      int e = t + 256*q;
      int r = e >> 6, c = e & 63;
      Bs[r][c] = W1[(k0+r)*HID + j0 + c];
    }
    __syncthreads();
    #pragma unroll
    for (int kk=0; kk<32; ++kk){
      float a0 = As[tm*2+0][kk], a1 = As[tm*2+1][kk];
      const float4 bv = *reinterpret_cast<const float4*>(&Bs[kk][tn*4]);
      acc[0][0] += a0*bv.x; acc[0][1] += a0*bv.y; acc[0][2] += a0*bv.z; acc[0][3] += a0*bv.w;
      acc[1][0] += a1*bv.x; acc[1][1] += a1*bv.y; acc[1][2] += a1*bv.z; acc[1][3] += a1*bv.w;
    }
    __syncthreads();
  }
  int bg = b0 + tm*2;
  int j = j0 + tn*4;
  #pragma unroll
  for (int r=0;r<2;++r){
    #pragma unroll
    for (int c=0;c<4;++c){
      float pre = acc[r][c] + b1[j+c];
      float v;
      if (MODE==0) v = (pre > 0.f) ? W2[j+c] : 0.f;
      else         v = fmaxf(pre, 0.f) * W2[j+c];
      out[(bg+r)*HID + j + c] = v;
    }
  }
}

// ---------------- backward matmul: k = -s .* (coef @ W1^T) ----------------
__global__ void bwd_mm(const float* __restrict__ Cf, const float* __restrict__ W1,
                       const float* __restrict__ sg, float* __restrict__ kout,
                       const int* __restrict__ flags){
  if (flags[0]) return;
  __shared__ float As[32][33]; // coef[b][j] chunk
  __shared__ float Bs[32][33]; // W1[i][j] chunk, Bs[i][kk]
  int i0 = blockIdx.x * 32;
  int b0 = blockIdx.y * 32;
  int t = threadIdx.x, tn = t & 15, tm = t >> 4;
  float acc[2][2] = {{0.f,0.f},{0.f,0.f}};
  for (int j0 = 0; j0 < HID; j0 += 32){
    #pragma unroll
    for (int q=0;q<4;++q){
      int e = t + 256*q; int r = e>>5, c = e&31;
      As[r][c] = Cf[(b0+r)*HID + j0 + c];
      Bs[r][c] = W1[(i0+r)*HID + j0 + c];
    }
    __syncthreads();
    #pragma unroll
    for (int kk=0;kk<32;++kk){
      float a0 = As[tm*2+0][kk], a1 = As[tm*2+1][kk];
      float bb0 = Bs[tn*2+0][kk], bb1 = Bs[tn*2+1][kk];
      acc[0][0]+=a0*bb0; acc[0][1]+=a0*bb1; acc[1][0]+=a1*bb0; acc[1][1]+=a1*bb1;
    }
    __syncthreads();
  }
  #pragma unroll
  for (int r=0;r<2;++r){
    #pragma unroll
    for (int c=0;c<2;++c){
      int bg = b0 + tm*2 + r, i = i0 + tn*2 + c;
      int idx = bg*DD + i;
      kout[idx] = -sg[idx]*acc[r][c];
    }
  }
}

// ---------------- combine: x_lo/x_hi, err = max|x_hi-x_lo| ----------------
__global__ void combine(const float* __restrict__ xs, const float* __restrict__ kbuf,
                        float* __restrict__ xhi, const float* __restrict__ scal,
                        const int* __restrict__ flags, unsigned* err_bits){
  if (flags[0]) return;
  __shared__ float red[BLK];
  int idx = blockIdx.x*BLK + threadIdx.x;
  float dt = scal[0];
  float k1 = kbuf[idx], k3 = kbuf[2*BD+idx], k4 = kbuf[3*BD+idx],
        k5 = kbuf[4*BD+idx], k6 = kbuf[5*BD+idx];
  float x = xs[idx];
  float xlo = x + dt*((float)(25.0/216.0)*k1 + (float)(1408.0/2565.0)*k3
                    + (float)(2197.0/4104.0)*k4 - k5*0.2f);
  float xh  = x + dt*((float)(16.0/135.0)*k1 + (float)(6656.0/12825.0)*k3
                    + (float)(28561.0/56430.0)*k4 - (float)(9.0/50.0)*k5
                    + (float)(2.0/55.0)*k6);
  xhi[idx] = xh;
  float d = fabsf(xh - xlo);
  red[threadIdx.x]=d; __syncthreads();
  for (int st=BLK/2; st>0; st>>=1){
    if (threadIdx.x<st) red[threadIdx.x]=fmaxf(red[threadIdx.x],red[threadIdx.x+st]);
    __syncthreads();
  }
  if (threadIdx.x==0) atomicMax(err_bits, __float_as_uint(red[0]));
}

// ---------------- scalar updates ----------------
__global__ void scalar1(float* scal, int* flags, const unsigned* err_bits){
  if (flags[0]){ flags[1]=0; return; }
  float err = __uint_as_float(*err_bits);
  float dt = scal[0];
  bool accept = (err <= TOL_) || (dt <= MIN_DT_ + 1e-9f);
  flags[1] = accept ? 1 : 0;          // upd = accept & ~done (done==0 here)
  if (accept) scal[1] = scal[1] + dt; // t += dt
  float grow = 0.9f*dt*powf(TOL_/(err+1e-12f), 0.2f);
  grow = fminf(fmaxf(grow, MIN_DT_), 1.0f);
  scal[0] = accept ? grow : fmaxf(dt*0.5f, MIN_DT_);
}

__global__ void update_x(float* __restrict__ xs, const float* __restrict__ xhi,
                         const int* __restrict__ flags){
  if (!flags[1]) return;
  int idx = blockIdx.x*BLK+threadIdx.x;
  xs[idx]=xhi[idx];
}

__global__ void reduce_E(const float* __restrict__ act, const float* __restrict__ b2,
                         float* __restrict__ prevE, const int* __restrict__ flags,
                         unsigned* rel_bits){
  if (flags[0] || !flags[1]) return;
  __shared__ float red[BLK];
  int b=blockIdx.x, t=threadIdx.x;
  float s=0.f;
  for (int j=t;j<HID;j+=BLK) s+=act[b*HID+j];
  red[t]=s; __syncthreads();
  for (int st=BLK/2; st>0; st>>=1){ if(t<st) red[t]+=red[t+st]; __syncthreads(); }
  if (t==0){
    float e = red[0] + b2[0];
    float pe = prevE[b];
    float r = fabsf(e-pe)/(fabsf(pe)+1e-8f);
    atomicMax(rel_bits, __float_as_uint(r));
    prevE[b]=e;   // prevE_n = where(upd, E, prevE); kernel only runs when upd
  }
}

__global__ void scalar2(float* scal, int* flags, const unsigned* rel_bits){
  if (flags[0] || !flags[1]) return;
  float t = scal[1];
  float rel = __uint_as_float(*rel_bits);
  if ((t > MAX_DELTA_T_) || ((t > 0.0f) && (rel < REL_TOL_))) flags[0]=1;
}

// ---------------- final: LN + linear(10) + softmax ----------------
__global__ void final_out(const float* __restrict__ xs, const float* __restrict__ g,
                          const float* __restrict__ bb, const float* __restrict__ Wo,
                          const float* __restrict__ bo, float* __restrict__ out){
  __shared__ float h[DD];
  __shared__ float red[BLK];
  __shared__ float logits[16];
  int b = blockIdx.x, t = threadIdx.x;
  float s=0.f;
  for (int i=t;i<DD;i+=BLK){ float v = xs[b*DD+i]; h[i]=v; s+=v; }
  red[t]=s; __syncthreads();
  for (int st=BLK/2; st>0; st>>=1){ if(t<st) red[t]+=red[t+st]; __syncthreads(); }
  float mean = red[0]/(float)DD; __syncthreads();
  float v2=0.f;
  for (int i=t;i<DD;i+=BLK){ float d=h[i]-mean; v2+=d*d; }
  red[t]=v2; __syncthreads();
  for (int st=BLK/2; st>0; st>>=1){ if(t<st) red[t]+=red[t+st]; __syncthreads(); }
  float var = red[0]/(float)DD; __syncthreads();
  float inv = 1.0f/sqrtf(var+LN_EPS_);
  float part[10];
  #pragma unroll
  for (int c=0;c<10;++c) part[c]=0.f;
  for (int i=t;i<DD;i+=BLK){
    float hn = (h[i]-mean)*inv*g[i] + bb[i];
    #pragma unroll
    for (int c=0;c<10;++c) part[c] += hn*Wo[i*10+c];
  }
  #pragma unroll
  for (int c=0;c<10;++c){
    red[t]=part[c]; __syncthreads();
    for (int st=BLK/2; st>0; st>>=1){ if(t<st) red[t]+=red[t+st]; __syncthreads(); }
    if (t==0) logits[c]=red[0]+bo[c];
    __syncthreads();
  }
  if (t==0){
    float m=logits[0];
    #pragma unroll
    for (int c=1;c<10;++c) m=fmaxf(m,logits[c]);
    float ssum=0.f; float e[10];
    #pragma unroll
    for (int c=0;c<10;++c){ e[c]=expf(logits[c]-m); ssum+=e[c]; }
    #pragma unroll
    for (int c=0;c<10;++c) out[b*10+c]=e[c]/ssum;
  }
}

extern "C" void kernel_launch(void* const* d_in, const int* in_sizes, int n_in,
                              void* d_out, int out_size, void* d_ws, size_t ws_size,
                              hipStream_t stream){
  const float* x   = (const float*)d_in[0];
  const float* g0  = (const float*)d_in[1];
  const float* bt0 = (const float*)d_in[2];
  const float* W1  = (const float*)d_in[3];
  const float* b1  = (const float*)d_in[4];
  const float* W2  = (const float*)d_in[5];
  const float* b2  = (const float*)d_in[6];
  const float* g1  = (const float*)d_in[7];
  const float* bt1 = (const float*)d_in[8];
  const float* Wo  = (const float*)d_in[9];
  const float* bo  = (const float*)d_in[10];
  float* out = (float*)d_out;

  float* w    = (float*)d_ws;
  float* xs   = w;                 // [B,D]
  float* kbuf = w + BD;            // 6 x [B,D]
  float* z    = w + 7*BD;          // [B,D]
  float* sg   = w + 8*BD;          // [B,D]
  float* xhi  = w + 9*BD;          // [B,D]
  float* coef = w + 10*BD;         // [B,HID] = 2*BD
  float* prevE= w + 12*BD;         // [B]
  float* scal = w + 12*BD + BB;    // [dt, t]
  unsigned* err_bits = (unsigned*)(scal + 8);
  unsigned* rel_bits = err_bits + 1;
  int* flags = (int*)(err_bits + 2); // [done, upd]

  pool_ln<<<BB, BLK, 0, stream>>>(x, g0, bt0, xs, scal, flags, prevE);

  for (int step=0; step<16; ++step){
    for (int st=1; st<=6; ++st){
      eval_point<<<BD/BLK, BLK, 0, stream>>>(xs, kbuf, z, sg, scal, flags, st, err_bits, rel_bits);
      fwd_mm<0><<<dim3(HID/64, BB/32), BLK, 0, stream>>>(z, W1, b1, W2, coef, flags, 0);
      bwd_mm<<<dim3(DD/32, BB/32), BLK, 0, stream>>>(coef, W1, sg, kbuf + (st-1)*BD, flags);
    }
    combine<<<BD/BLK, BLK, 0, stream>>>(xs, kbuf, xhi, scal, flags, err_bits);
    scalar1<<<1, 1, 0, stream>>>(scal, flags, err_bits);
    update_x<<<BD/BLK, BLK, 0, stream>>>(xs, xhi, flags);
    fwd_mm<1><<<dim3(HID/64, BB/32), BLK, 0, stream>>>(xs, W1, b1, W2, coef, flags, 1);
    reduce_E<<<BB, BLK, 0, stream>>>(coef, b2, prevE, flags, rel_bits);
    scalar2<<<1, 1, 0, stream>>>(scal, flags, rel_bits);
  }

  final_out<<<BB, BLK, 0, stream>>>(xs, g1, bt1, Wo, bo, out);
}

// Round 3
// 6672.691 us; speedup vs baseline: 1.9502x; 1.9502x over previous
//
#include <hip/hip_runtime.h>
#include <math.h>

#define BB 128
#define IMG 64
#define DD 1024
#define HID 2048
#define BD (BB*DD)
#define BLK 256

#define DT0 0.1f
#define TOL_ 0.01f
#define MIN_DT_ 0.1f
#define MAX_DELTA_T_ 20.0f
#define REL_TOL_ 1e-3f
#define LN_EPS_ 1e-3f

// RKF56 stage coefficients (a_ij), row = stage-1
__constant__ float RKA[6][5] = {
  {0.f,0.f,0.f,0.f,0.f},
  {0.25f,0.f,0.f,0.f,0.f},
  {(float)(3.0/32.0),(float)(9.0/32.0),0.f,0.f,0.f},
  {(float)(1932.0/2197.0),(float)(-7200.0/2197.0),(float)(7296.0/2197.0),0.f,0.f},
  {(float)(439.0/216.0),-8.0f,(float)(3680.0/513.0),(float)(-845.0/4104.0),0.f},
  {(float)(-8.0/27.0),2.0f,(float)(-3544.0/2565.0),(float)(1859.0/4104.0),(float)(-11.0/40.0)}
};

__device__ __forceinline__ void reflect(float x, float& zv, float& sv){
  int ii = (int)x;                 // trunc toward zero == astype(int32)
  bool odd = (ii & 1) != 0;
  zv = odd ? (1.0f - x) : x;
  sv = odd ? -1.0f : 1.0f;
}

// ---------------- maxpool 2x2 + layernorm + state/z/sg init ----------------
__global__ void pool_ln(const float* __restrict__ x, const float* __restrict__ g,
                        const float* __restrict__ bb, float* __restrict__ xs,
                        float* __restrict__ z, float* __restrict__ sg,
                        float* __restrict__ scal, int* __restrict__ flags,
                        float* __restrict__ prevE, unsigned* err_bits, unsigned* rel_bits){
  __shared__ float p[DD];
  __shared__ float red[BLK];
  int b = blockIdx.x, t = threadIdx.x;
  const float* xb = x + b*IMG*IMG;
  for (int idx=t; idx<DD; idx+=BLK){
    int r = idx>>5, c = idx&31;
    const float* base = xb + (r*2)*IMG + c*2;
    p[idx] = fmaxf(fmaxf(base[0], base[1]), fmaxf(base[IMG], base[IMG+1]));
  }
  __syncthreads();
  float s=0.f;
  for (int idx=t; idx<DD; idx+=BLK) s += p[idx];
  red[t]=s; __syncthreads();
  for (int st=BLK/2; st>0; st>>=1){ if (t<st) red[t]+=red[t+st]; __syncthreads(); }
  float mean = red[0]/(float)DD; __syncthreads();
  float v=0.f;
  for (int idx=t; idx<DD; idx+=BLK){ float d=p[idx]-mean; v+=d*d; }
  red[t]=v; __syncthreads();
  for (int st=BLK/2; st>0; st>>=1){ if (t<st) red[t]+=red[t+st]; __syncthreads(); }
  float var = red[0]/(float)DD;
  float inv = 1.0f/sqrtf(var + LN_EPS_);
  for (int idx=t; idx<DD; idx+=BLK){
    float val = (p[idx]-mean)*inv*g[idx] + bb[idx];
    xs[b*DD+idx] = val;
    float zv, sv; reflect(val, zv, sv);
    z[b*DD+idx] = zv; sg[b*DD+idx] = sv;
  }
  if (b==0){
    if (t==0){ scal[0]=DT0; scal[1]=0.f; flags[0]=0; flags[1]=0; *err_bits=0u; *rel_bits=0u; }
    if (t<BB) prevE[t]=0.f;
  }
}

// ---------------- forward matmul partials: part[kc] = A[:,chunk] @ W1[chunk,:] ----------------
// grid (16 n-tiles of 128, 2 m-tiles of 64, 8 k-chunks of 128), 512 threads.
// No epilogue: raw partial sums; bias+mask folded by consumers.
template<int GUARD_UPD>
__global__ __launch_bounds__(512)
void fwd_mm(const float* __restrict__ A, const float* __restrict__ W1,
            float* __restrict__ part, const int* __restrict__ flags){
  if (flags[0]) return;
  if (GUARD_UPD && !flags[1]) return;
  __shared__ float As[64][34];    // [m][kk]
  __shared__ float Bs[128][34];   // [n][kk]
  int j0 = blockIdx.x * 128;
  int b0 = blockIdx.y * 64;
  int kbase = blockIdx.z * 128;
  int t = threadIdx.x;
  int tn = t & 31, tm = t >> 5;   // tn 0..31, tm 0..15
  float acc[4][4] = {{0.f}};
  for (int k0 = 0; k0 < 128; k0 += 32){
    {
      int c = t & 31, r0 = t >> 5;          // coalesced over k
      #pragma unroll
      for (int q=0;q<4;++q){
        int r = r0 + 16*q;
        As[r][c] = A[(b0+r)*DD + kbase + k0 + c];
      }
    }
    {
      int n = t & 127, kk0 = t >> 7;        // coalesced over j
      #pragma unroll
      for (int q=0;q<8;++q){
        int kk = kk0 + 4*q;
        Bs[n][kk] = W1[(kbase+k0+kk)*HID + j0 + n];
      }
    }
    __syncthreads();
    #pragma unroll
    for (int p=0;p<16;++p){
      float2 a[4], bv[4];
      #pragma unroll
      for (int i=0;i<4;++i) a[i]  = *(const float2*)&As[tm+16*i][2*p];
      #pragma unroll
      for (int j=0;j<4;++j) bv[j] = *(const float2*)&Bs[tn+32*j][2*p];
      #pragma unroll
      for (int i=0;i<4;++i)
        #pragma unroll
        for (int j=0;j<4;++j)
          acc[i][j] += a[i].x*bv[j].x + a[i].y*bv[j].y;
    }
    __syncthreads();
  }
  float* dst = part + (size_t)blockIdx.z * (BB*HID);
  #pragma unroll
  for (int i=0;i<4;++i){
    int b = b0 + tm + 16*i;
    #pragma unroll
    for (int j=0;j<4;++j)
      dst[b*HID + j0 + tn + 32*j] = acc[i][j];
  }
}

// ---------------- backward matmul partials: bpart[kc] = coef[:,chunk] @ W1[:,chunk]^T ----------------
// coef folded inline from the 8 fwd partials + bias + mask.
// grid (8 i-tiles of 128, 2 b-tiles of 64, 16 j-chunks of 128), 512 threads.
__global__ __launch_bounds__(512)
void bwd_mm(const float* __restrict__ fpart, const float* __restrict__ b1,
            const float* __restrict__ W2, const float* __restrict__ W1,
            float* __restrict__ bpart, const int* __restrict__ flags){
  if (flags[0]) return;
  __shared__ float As[64][34];    // coef [b][jj]
  __shared__ float Bs[128][34];   // W1   [i][jj]
  int i0 = blockIdx.x * 128;
  int b0 = blockIdx.y * 64;
  int jbase = blockIdx.z * 128;
  int t = threadIdx.x;
  int tn = t & 31, tm = t >> 5;
  float acc[4][4] = {{0.f}};
  for (int j0 = 0; j0 < 128; j0 += 32){
    {
      int c = t & 31, r0 = t >> 5;
      int jg = jbase + j0 + c;
      float b1v = b1[jg], w2v = W2[jg];
      #pragma unroll
      for (int q=0;q<4;++q){
        int r = r0 + 16*q;                 // batch row
        int idx = (b0+r)*HID + jg;
        float pre = b1v;
        #pragma unroll
        for (int c8=0;c8<8;++c8) pre += fpart[c8*(BB*HID) + idx];
        As[r][c] = (pre > 0.f) ? w2v : 0.f;
      }
    }
    {
      int c = t & 31, r0 = t >> 5;
      #pragma unroll
      for (int q=0;q<8;++q){
        int r = r0 + 16*q;                 // i row 0..127
        Bs[r][c] = W1[(i0+r)*HID + jbase + j0 + c];
      }
    }
    __syncthreads();
    #pragma unroll
    for (int p=0;p<16;++p){
      float2 a[4], bv[4];
      #pragma unroll
      for (int i=0;i<4;++i) a[i]  = *(const float2*)&As[tm+16*i][2*p];
      #pragma unroll
      for (int j=0;j<4;++j) bv[j] = *(const float2*)&Bs[tn+32*j][2*p];
      #pragma unroll
      for (int i=0;i<4;++i)
        #pragma unroll
        for (int j=0;j<4;++j)
          acc[i][j] += a[i].x*bv[j].x + a[i].y*bv[j].y;
    }
    __syncthreads();
  }
  float* dst = bpart + (size_t)blockIdx.z * BD;
  #pragma unroll
  for (int i=0;i<4;++i){
    int b = b0 + tm + 16*i;
    #pragma unroll
    for (int j=0;j<4;++j)
      dst[b*DD + i0 + tn + 32*j] = acc[i][j];
  }
}

// ---------------- fold bwd partials -> k_s; next eval point (or combine+err) ----------------
__global__ void reduce_eval(const float* __restrict__ bpart, float* __restrict__ kbuf,
                            const float* __restrict__ xs, float* __restrict__ z,
                            float* __restrict__ sg, float* __restrict__ xhi,
                            const float* __restrict__ scal, const int* __restrict__ flags,
                            unsigned* err_bits, int s){
  if (flags[0]) return;
  int idx = blockIdx.x*BLK + threadIdx.x;
  float sum = 0.f;
  #pragma unroll
  for (int c=0;c<16;++c) sum += bpart[c*BD + idx];
  float ks = -sg[idx]*sum;
  kbuf[(s-1)*BD + idx] = ks;
  float dt = scal[0];
  if (s < 6){
    float acc = RKA[s][s-1]*ks;
    for (int m=0;m<s-1;++m) acc += RKA[s][m]*kbuf[m*BD+idx];
    float xe = xs[idx] + dt*acc;
    float zv, sv; reflect(xe, zv, sv);
    z[idx]=zv; sg[idx]=sv;
  } else {
    __shared__ float red[BLK];
    float k1 = kbuf[idx], k3 = kbuf[2*BD+idx], k4 = kbuf[3*BD+idx], k5 = kbuf[4*BD+idx];
    float k6 = ks;
    float x = xs[idx];
    float xlo = x + dt*((float)(25.0/216.0)*k1 + (float)(1408.0/2565.0)*k3
                      + (float)(2197.0/4104.0)*k4 - k5*0.2f);
    float xh  = x + dt*((float)(16.0/135.0)*k1 + (float)(6656.0/12825.0)*k3
                      + (float)(28561.0/56430.0)*k4 - (float)(9.0/50.0)*k5
                      + (float)(2.0/55.0)*k6);
    xhi[idx] = xh;
    float d = fabsf(xh - xlo);
    red[threadIdx.x]=d; __syncthreads();
    for (int st=BLK/2; st>0; st>>=1){
      if (threadIdx.x<st) red[threadIdx.x]=fmaxf(red[threadIdx.x],red[threadIdx.x+st]);
      __syncthreads();
    }
    if (threadIdx.x==0) atomicMax(err_bits, __float_as_uint(red[0]));
  }
}

// ---------------- scalar update 1 (accept/dt) ----------------
__global__ void scalar1(float* scal, int* flags, unsigned* err_bits){
  if (flags[0]){ flags[1]=0; return; }
  float err = __uint_as_float(*err_bits);
  *err_bits = 0u;
  float dt = scal[0];
  bool accept = (err <= TOL_) || (dt <= MIN_DT_ + 1e-9f);
  flags[1] = accept ? 1 : 0;
  if (accept) scal[1] = scal[1] + dt;
  float grow = 0.9f*dt*powf(TOL_/(err+1e-12f), 0.2f);
  grow = fminf(fmaxf(grow, MIN_DT_), 1.0f);
  scal[0] = accept ? grow : fmaxf(dt*0.5f, MIN_DT_);
}

// ---------------- commit x (if accepted) + stage-1 eval point for next step ----------------
__global__ void update_eval(float* __restrict__ xs, const float* __restrict__ xhi,
                            float* __restrict__ z, float* __restrict__ sg,
                            const int* __restrict__ flags){
  if (flags[0]) return;
  int idx = blockIdx.x*BLK + threadIdx.x;
  float x = flags[1] ? xhi[idx] : xs[idx];
  xs[idx] = x;
  float zv, sv; reflect(x, zv, sv);
  z[idx]=zv; sg[idx]=sv;
}

// ---------------- energy reduce: fold fwd partials, relu*W2, row-sum ----------------
__global__ void reduce_E(const float* __restrict__ fpart, const float* __restrict__ b1,
                         const float* __restrict__ W2, const float* __restrict__ b2,
                         float* __restrict__ prevE, const int* __restrict__ flags,
                         unsigned* rel_bits){
  if (flags[0] || !flags[1]) return;
  __shared__ float red[BLK];
  int b=blockIdx.x, t=threadIdx.x;
  float s=0.f;
  for (int j=t;j<HID;j+=BLK){
    float pre = b1[j];
    #pragma unroll
    for (int c8=0;c8<8;++c8) pre += fpart[c8*(BB*HID) + b*HID + j];
    s += fmaxf(pre,0.f)*W2[j];
  }
  red[t]=s; __syncthreads();
  for (int st=BLK/2; st>0; st>>=1){ if(t<st) red[t]+=red[t+st]; __syncthreads(); }
  if (t==0){
    float e = red[0] + b2[0];
    float pe = prevE[b];
    float r = fabsf(e-pe)/(fabsf(pe)+1e-8f);
    atomicMax(rel_bits, __float_as_uint(r));
    prevE[b]=e;
  }
}

__global__ void scalar2(float* scal, int* flags, unsigned* rel_bits){
  if (flags[0] || !flags[1]) return;
  float t = scal[1];
  float rel = __uint_as_float(*rel_bits);
  *rel_bits = 0u;
  if ((t > MAX_DELTA_T_) || ((t > 0.0f) && (rel < REL_TOL_))) flags[0]=1;
}

// ---------------- final: LN + linear(10) + softmax ----------------
__global__ void final_out(const float* __restrict__ xs, const float* __restrict__ g,
                          const float* __restrict__ bb, const float* __restrict__ Wo,
                          const float* __restrict__ bo, float* __restrict__ out){
  __shared__ float h[DD];
  __shared__ float red[BLK];
  __shared__ float logits[16];
  int b = blockIdx.x, t = threadIdx.x;
  float s=0.f;
  for (int i=t;i<DD;i+=BLK){ float v = xs[b*DD+i]; h[i]=v; s+=v; }
  red[t]=s; __syncthreads();
  for (int st=BLK/2; st>0; st>>=1){ if(t<st) red[t]+=red[t+st]; __syncthreads(); }
  float mean = red[0]/(float)DD; __syncthreads();
  float v2=0.f;
  for (int i=t;i<DD;i+=BLK){ float d=h[i]-mean; v2+=d*d; }
  red[t]=v2; __syncthreads();
  for (int st=BLK/2; st>0; st>>=1){ if(t<st) red[t]+=red[t+st]; __syncthreads(); }
  float var = red[0]/(float)DD; __syncthreads();
  float inv = 1.0f/sqrtf(var+LN_EPS_);
  float part[10];
  #pragma unroll
  for (int c=0;c<10;++c) part[c]=0.f;
  for (int i=t;i<DD;i+=BLK){
    float hn = (h[i]-mean)*inv*g[i] + bb[i];
    #pragma unroll
    for (int c=0;c<10;++c) part[c] += hn*Wo[i*10+c];
  }
  #pragma unroll
  for (int c=0;c<10;++c){
    red[t]=part[c]; __syncthreads();
    for (int st=BLK/2; st>0; st>>=1){ if(t<st) red[t]+=red[t+st]; __syncthreads(); }
    if (t==0) logits[c]=red[0]+bo[c];
    __syncthreads();
  }
  if (t==0){
    float m=logits[0];
    #pragma unroll
    for (int c=1;c<10;++c) m=fmaxf(m,logits[c]);
    float ssum=0.f; float e[10];
    #pragma unroll
    for (int c=0;c<10;++c){ e[c]=expf(logits[c]-m); ssum+=e[c]; }
    #pragma unroll
    for (int c=0;c<10;++c) out[b*10+c]=e[c]/ssum;
  }
}

extern "C" void kernel_launch(void* const* d_in, const int* in_sizes, int n_in,
                              void* d_out, int out_size, void* d_ws, size_t ws_size,
                              hipStream_t stream){
  const float* x   = (const float*)d_in[0];
  const float* g0  = (const float*)d_in[1];
  const float* bt0 = (const float*)d_in[2];
  const float* W1  = (const float*)d_in[3];
  const float* b1  = (const float*)d_in[4];
  const float* W2  = (const float*)d_in[5];
  const float* b2  = (const float*)d_in[6];
  const float* g1  = (const float*)d_in[7];
  const float* bt1 = (const float*)d_in[8];
  const float* Wo  = (const float*)d_in[9];
  const float* bo  = (const float*)d_in[10];
  float* out = (float*)d_out;

  float* w     = (float*)d_ws;
  float* xs    = w;             // BD
  float* xhi   = w + (size_t)BD;
  float* z     = w + (size_t)2*BD;
  float* sg    = w + (size_t)3*BD;
  float* kbuf  = w + (size_t)4*BD;   // 6*BD
  float* fpart = w + (size_t)10*BD;  // 8 * (B*HID) = 16*BD
  float* bpart = w + (size_t)26*BD;  // 16 * BD
  float* prevE = w + (size_t)42*BD;  // BB
  float* scal  = prevE + BB;         // dt, t
  unsigned* err_bits = (unsigned*)(scal + 4);
  unsigned* rel_bits = err_bits + 1;
  int* flags = (int*)(err_bits + 2); // [done, upd]

  pool_ln<<<BB, BLK, 0, stream>>>(x, g0, bt0, xs, z, sg, scal, flags, prevE, err_bits, rel_bits);

  for (int step=0; step<16; ++step){
    for (int s=1; s<=6; ++s){
      fwd_mm<0><<<dim3(16,2,8), 512, 0, stream>>>(z, W1, fpart, flags);
      bwd_mm<<<dim3(8,2,16), 512, 0, stream>>>(fpart, b1, W2, W1, bpart, flags);
      reduce_eval<<<BD/BLK, BLK, 0, stream>>>(bpart, kbuf, xs, z, sg, xhi, scal, flags, err_bits, s);
    }
    scalar1<<<1, 1, 0, stream>>>(scal, flags, err_bits);
    update_eval<<<BD/BLK, BLK, 0, stream>>>(xs, xhi, z, sg, flags);
    fwd_mm<1><<<dim3(16,2,8), 512, 0, stream>>>(xs, W1, fpart, flags);
    reduce_E<<<BB, BLK, 0, stream>>>(fpart, b1, W2, b2, prevE, flags, rel_bits);
    scalar2<<<1, 1, 0, stream>>>(scal, flags, rel_bits);
  }

  final_out<<<BB, BLK, 0, stream>>>(xs, g1, bt1, Wo, bo, out);
}

// Round 5
// 5078.332 us; speedup vs baseline: 2.5624x; 1.3140x over previous
//
#include <hip/hip_runtime.h>
#include <math.h>

#define BB 128
#define IMG 64
#define DD 1024
#define HID 2048
#define BD (BB*DD)
#define BLK 256

#define DT0 0.1f
#define TOL_ 0.01f
#define MIN_DT_ 0.1f
#define MAX_DELTA_T_ 20.0f
#define REL_TOL_ 1e-3f
#define LN_EPS_ 1e-3f

// RKF56 stage coefficients (a_ij), row = stage-1
__constant__ float RKA[6][5] = {
  {0.f,0.f,0.f,0.f,0.f},
  {0.25f,0.f,0.f,0.f,0.f},
  {(float)(3.0/32.0),(float)(9.0/32.0),0.f,0.f,0.f},
  {(float)(1932.0/2197.0),(float)(-7200.0/2197.0),(float)(7296.0/2197.0),0.f,0.f},
  {(float)(439.0/216.0),-8.0f,(float)(3680.0/513.0),(float)(-845.0/4104.0),0.f},
  {(float)(-8.0/27.0),2.0f,(float)(-3544.0/2565.0),(float)(1859.0/4104.0),(float)(-11.0/40.0)}
};

__device__ __forceinline__ void reflect(float x, float& zv, float& sv){
  int ii = (int)x;                 // trunc toward zero == astype(int32)
  bool odd = (ii & 1) != 0;
  zv = odd ? (1.0f - x) : x;
  sv = odd ? -1.0f : 1.0f;
}

// ---------------- maxpool 2x2 + layernorm + state/z/sg init ----------------
__global__ void pool_ln(const float* __restrict__ x, const float* __restrict__ g,
                        const float* __restrict__ bb, float* __restrict__ xs,
                        float* __restrict__ z, float* __restrict__ sg,
                        float* __restrict__ scal, int* __restrict__ flags,
                        float* __restrict__ prevE, unsigned* err_bits, unsigned* rel_bits,
                        unsigned* ctr1, unsigned* ctr2){
  __shared__ float p[DD];
  __shared__ float red[BLK];
  int b = blockIdx.x, t = threadIdx.x;
  const float* xb = x + b*IMG*IMG;
  for (int idx=t; idx<DD; idx+=BLK){
    int r = idx>>5, c = idx&31;
    const float* base = xb + (r*2)*IMG + c*2;
    p[idx] = fmaxf(fmaxf(base[0], base[1]), fmaxf(base[IMG], base[IMG+1]));
  }
  __syncthreads();
  float s=0.f;
  for (int idx=t; idx<DD; idx+=BLK) s += p[idx];
  red[t]=s; __syncthreads();
  for (int st=BLK/2; st>0; st>>=1){ if (t<st) red[t]+=red[t+st]; __syncthreads(); }
  float mean = red[0]/(float)DD; __syncthreads();
  float v=0.f;
  for (int idx=t; idx<DD; idx+=BLK){ float d=p[idx]-mean; v+=d*d; }
  red[t]=v; __syncthreads();
  for (int st=BLK/2; st>0; st>>=1){ if (t<st) red[t]+=red[t+st]; __syncthreads(); }
  float var = red[0]/(float)DD;
  float inv = 1.0f/sqrtf(var + LN_EPS_);
  for (int idx=t; idx<DD; idx+=BLK){
    float val = (p[idx]-mean)*inv*g[idx] + bb[idx];
    xs[b*DD+idx] = val;
    float zv, sv; reflect(val, zv, sv);
    z[b*DD+idx] = zv; sg[b*DD+idx] = sv;
  }
  if (b==0){
    if (t==0){
      scal[0]=DT0; scal[1]=0.f; flags[0]=0; flags[1]=0;
      *err_bits=0u; *rel_bits=0u; *ctr1=0u; *ctr2=0u;
    }
    if (t<BB) prevE[t]=0.f;
  }
}

// ---------------- forward matmul partials ----------------
// grid (16 n-tiles of 128, 16 k-chunks of 64), 256 thr. tile M=128 N=128 K=64.
// Per-thread 8x8: rows rr+16i, cols (cc*4+64j)+u. One LDS stage, one barrier.
template<int GUARD>
__global__ __launch_bounds__(256)
void fwd_mm(const float* __restrict__ A, const float* __restrict__ W1,
            float* __restrict__ fpart, const int* __restrict__ flags){
  if (flags[0]) return;
  if (GUARD && !flags[1]) return;
  __shared__ float As[128][68];   // [m][kk], pad 68: frag reads bank-free
  __shared__ float Bs[64][132];   // [kk][n], pad 132: b128 frag reads bank-free
  int n0 = blockIdx.x * 128;
  int kb = blockIdx.y * 64;
  int t  = threadIdx.x;
  #pragma unroll
  for (int q=0;q<8;++q){
    int e = t + 256*q;
    int m = e >> 4, c4 = (e & 15)*4;
    float4 v = *(const float4*)&A[m*DD + kb + c4];
    *(float4*)&As[m][c4] = v;
  }
  #pragma unroll
  for (int q=0;q<8;++q){
    int e = t + 256*q;
    int kk = e >> 5, c4 = (e & 31)*4;
    float4 v = *(const float4*)&W1[(size_t)(kb+kk)*HID + n0 + c4];
    *(float4*)&Bs[kk][c4] = v;
  }
  __syncthreads();
  int rr = t >> 4, cc = t & 15;
  float acc[8][8] = {{0.f}};
  #pragma unroll 4
  for (int kk=0; kk<64; ++kk){
    float a[8];
    #pragma unroll
    for (int i=0;i<8;++i) a[i] = As[rr + 16*i][kk];
    float4 bv0 = *(const float4*)&Bs[kk][cc*4];
    float4 bv1 = *(const float4*)&Bs[kk][cc*4 + 64];
    #pragma unroll
    for (int i=0;i<8;++i){
      acc[i][0] += a[i]*bv0.x; acc[i][1] += a[i]*bv0.y;
      acc[i][2] += a[i]*bv0.z; acc[i][3] += a[i]*bv0.w;
      acc[i][4] += a[i]*bv1.x; acc[i][5] += a[i]*bv1.y;
      acc[i][6] += a[i]*bv1.z; acc[i][7] += a[i]*bv1.w;
    }
  }
  float* dst = fpart + (size_t)blockIdx.y * (BB*HID);
  #pragma unroll
  for (int i=0;i<8;++i){
    int m = rr + 16*i;
    float4 o0 = {acc[i][0],acc[i][1],acc[i][2],acc[i][3]};
    float4 o1 = {acc[i][4],acc[i][5],acc[i][6],acc[i][7]};
    *(float4*)&dst[(size_t)m*HID + n0 + cc*4]      = o0;
    *(float4*)&dst[(size_t)m*HID + n0 + cc*4 + 64] = o1;
  }
}

// ---------------- fold 16 fwd partials -> coef = mask(pre)*W2 ----------------
__global__ __launch_bounds__(256)
void coef_fold(const float* __restrict__ fpart, const float* __restrict__ b1,
               const float* __restrict__ W2, float* __restrict__ coef,
               const int* __restrict__ flags){
  if (flags[0]) return;
  int i4 = blockIdx.x*256 + threadIdx.x;   // float4 index over B*HID/4 = 65536
  int j4 = (i4 & 511) * 4;                 // column (HID) base
  float4 pre = *(const float4*)&b1[j4];
  #pragma unroll
  for (int c=0;c<16;++c){
    float4 v = *(const float4*)&fpart[(size_t)c*(BB*HID) + (size_t)i4*4];
    pre.x+=v.x; pre.y+=v.y; pre.z+=v.z; pre.w+=v.w;
  }
  float4 w2 = *(const float4*)&W2[j4];
  float4 o;
  o.x = pre.x>0.f ? w2.x : 0.f;
  o.y = pre.y>0.f ? w2.y : 0.f;
  o.z = pre.z>0.f ? w2.z : 0.f;
  o.w = pre.w>0.f ? w2.w : 0.f;
  *(float4*)&coef[(size_t)i4*4] = o;
}

// ---------------- backward matmul partials: bpart[jc] = coef[:,chunk] @ W1[:,chunk]^T --------
// grid (8 i-tiles of 128, 32 j-chunks of 64), 256 thr. tile M=128(b) N=128(i) K=64(jj).
__global__ __launch_bounds__(256)
void bwd_mm(const float* __restrict__ coef, const float* __restrict__ W1,
            float* __restrict__ bpart, const int* __restrict__ flags){
  if (flags[0]) return;
  __shared__ float As[128][68];   // coef [b][jj]
  __shared__ float Bs[128][68];   // W1   [i][jj]
  int i0 = blockIdx.x * 128;
  int jb = blockIdx.y * 64;
  int t = threadIdx.x;
  #pragma unroll
  for (int q=0;q<8;++q){
    int e = t + 256*q;
    int r = e >> 4, c4 = (e & 15)*4;
    *(float4*)&As[r][c4] = *(const float4*)&coef[(size_t)r*HID + jb + c4];
    *(float4*)&Bs[r][c4] = *(const float4*)&W1[(size_t)(i0+r)*HID + jb + c4];
  }
  __syncthreads();
  int rr = t >> 4, cc = t & 15;
  float acc[8][8] = {{0.f}};
  #pragma unroll 4
  for (int kk=0; kk<64; ++kk){
    float a[8], b[8];
    #pragma unroll
    for (int i=0;i<8;++i) a[i] = As[rr + 16*i][kk];
    #pragma unroll
    for (int j=0;j<8;++j) b[j] = Bs[cc + 16*j][kk];
    #pragma unroll
    for (int i=0;i<8;++i)
      #pragma unroll
      for (int j=0;j<8;++j)
        acc[i][j] += a[i]*b[j];
  }
  float* dst = bpart + (size_t)blockIdx.y * BD;
  #pragma unroll
  for (int i=0;i<8;++i){
    int bg = rr + 16*i;
    #pragma unroll
    for (int j=0;j<8;++j)
      dst[(size_t)bg*DD + i0 + cc + 16*j] = acc[i][j];
  }
}

// ---------------- fold 32 bwd partials -> k_s; next eval point (or combine+err+scalar1) ----
__global__ void reduce_eval(const float* __restrict__ bpart, float* __restrict__ kbuf,
                            const float* __restrict__ xs, float* __restrict__ z,
                            float* __restrict__ sg, float* __restrict__ xhi,
                            float* __restrict__ scal, int* __restrict__ flags,
                            unsigned* err_bits, unsigned* ctr1, int s){
  if (flags[0]) return;
  int idx = blockIdx.x*BLK + threadIdx.x;
  float sum = 0.f;
  #pragma unroll
  for (int c=0;c<32;++c) sum += bpart[(size_t)c*BD + idx];
  float ks = -sg[idx]*sum;
  kbuf[(size_t)(s-1)*BD + idx] = ks;
  float dt = scal[0];
  if (s < 6){
    float acc = RKA[s][s-1]*ks;
    for (int m=0;m<s-1;++m) acc += RKA[s][m]*kbuf[(size_t)m*BD+idx];
    float xe = xs[idx] + dt*acc;
    float zv, sv; reflect(xe, zv, sv);
    z[idx]=zv; sg[idx]=sv;
  } else {
    __shared__ float red[BLK];
    float k1 = kbuf[idx], k3 = kbuf[2*(size_t)BD+idx], k4 = kbuf[3*(size_t)BD+idx],
          k5 = kbuf[4*(size_t)BD+idx];
    float k6 = ks;
    float x = xs[idx];
    float xlo = x + dt*((float)(25.0/216.0)*k1 + (float)(1408.0/2565.0)*k3
                      + (float)(2197.0/4104.0)*k4 - k5*0.2f);
    float xh  = x + dt*((float)(16.0/135.0)*k1 + (float)(6656.0/12825.0)*k3
                      + (float)(28561.0/56430.0)*k4 - (float)(9.0/50.0)*k5
                      + (float)(2.0/55.0)*k6);
    xhi[idx] = xh;
    float d = fabsf(xh - xlo);
    red[threadIdx.x]=d; __syncthreads();
    for (int st=BLK/2; st>0; st>>=1){
      if (threadIdx.x<st) red[threadIdx.x]=fmaxf(red[threadIdx.x],red[threadIdx.x+st]);
      __syncthreads();
    }
    if (threadIdx.x==0){
      atomicMax(err_bits, __float_as_uint(red[0]));
      __threadfence();
      unsigned tk = atomicAdd(ctr1, 1u);
      if (tk == 511u){                      // last of 512 blocks: scalar1
        *ctr1 = 0u;
        float err = __uint_as_float(atomicExch(err_bits, 0u));
        float dtc = scal[0];
        bool accept = (err <= TOL_) || (dtc <= MIN_DT_ + 1e-9f);
        flags[1] = accept ? 1 : 0;
        if (accept) scal[1] = scal[1] + dtc;
        float grow = 0.9f*dtc*powf(TOL_/(err+1e-12f), 0.2f);
        grow = fminf(fmaxf(grow, MIN_DT_), 1.0f);
        scal[0] = accept ? grow : fmaxf(dtc*0.5f, MIN_DT_);
      }
    }
  }
}

// ---------------- commit x (if accepted) + stage-1 eval point for next step ----------------
__global__ void update_eval(float* __restrict__ xs, const float* __restrict__ xhi,
                            float* __restrict__ z, float* __restrict__ sg,
                            const int* __restrict__ flags){
  if (flags[0]) return;
  int idx = blockIdx.x*BLK + threadIdx.x;
  float x = flags[1] ? xhi[idx] : xs[idx];
  xs[idx] = x;
  float zv, sv; reflect(x, zv, sv);
  z[idx]=zv; sg[idx]=sv;
}

// ---------------- energy reduce: fold 16 fwd partials, relu*W2, row-sum; scalar2 ----------
__global__ void reduce_E(const float* __restrict__ fpart, const float* __restrict__ b1,
                         const float* __restrict__ W2, const float* __restrict__ b2,
                         float* __restrict__ prevE, int* __restrict__ flags,
                         unsigned* rel_bits, float* __restrict__ scal, unsigned* ctr2){
  if (flags[0] || !flags[1]) return;
  __shared__ float red[BLK];
  int b=blockIdx.x, t=threadIdx.x;
  float s=0.f;
  for (int j=t;j<HID;j+=BLK){
    float pre = b1[j];
    #pragma unroll
    for (int c=0;c<16;++c) pre += fpart[(size_t)c*(BB*HID) + (size_t)b*HID + j];
    s += fmaxf(pre,0.f)*W2[j];
  }
  red[t]=s; __syncthreads();
  for (int st=BLK/2; st>0; st>>=1){ if(t<st) red[t]+=red[t+st]; __syncthreads(); }
  if (t==0){
    float e = red[0] + b2[0];
    float pe = prevE[b];
    float r = fabsf(e-pe)/(fabsf(pe)+1e-8f);
    atomicMax(rel_bits, __float_as_uint(r));
    prevE[b]=e;
    __threadfence();
    unsigned tk = atomicAdd(ctr2, 1u);
    if (tk == 127u){                        // last of 128 blocks: scalar2
      *ctr2 = 0u;
      float tn = scal[1];
      float rel = __uint_as_float(atomicExch(rel_bits, 0u));
      if ((tn > MAX_DELTA_T_) || ((tn > 0.0f) && (rel < REL_TOL_))) flags[0]=1;
    }
  }
}

// ---------------- final: LN + linear(10) + softmax ----------------
__global__ void final_out(const float* __restrict__ xs, const float* __restrict__ g,
                          const float* __restrict__ bb, const float* __restrict__ Wo,
                          const float* __restrict__ bo, float* __restrict__ out){
  __shared__ float h[DD];
  __shared__ float red[BLK];
  __shared__ float logits[16];
  int b = blockIdx.x, t = threadIdx.x;
  float s=0.f;
  for (int i=t;i<DD;i+=BLK){ float v = xs[b*DD+i]; h[i]=v; s+=v; }
  red[t]=s; __syncthreads();
  for (int st=BLK/2; st>0; st>>=1){ if(t<st) red[t]+=red[t+st]; __syncthreads(); }
  float mean = red[0]/(float)DD; __syncthreads();
  float v2=0.f;
  for (int i=t;i<DD;i+=BLK){ float d=h[i]-mean; v2+=d*d; }
  red[t]=v2; __syncthreads();
  for (int st=BLK/2; st>0; st>>=1){ if(t<st) red[t]+=red[t+st]; __syncthreads(); }
  float var = red[0]/(float)DD; __syncthreads();
  float inv = 1.0f/sqrtf(var+LN_EPS_);
  float part[10];
  #pragma unroll
  for (int c=0;c<10;++c) part[c]=0.f;
  for (int i=t;i<DD;i+=BLK){
    float hn = (h[i]-mean)*inv*g[i] + bb[i];
    #pragma unroll
    for (int c=0;c<10;++c) part[c] += hn*Wo[i*10+c];
  }
  #pragma unroll
  for (int c=0;c<10;++c){
    red[t]=part[c]; __syncthreads();
    for (int st=BLK/2; st>0; st>>=1){ if(t<st) red[t]+=red[t+st]; __syncthreads(); }
    if (t==0) logits[c]=red[0]+bo[c];
    __syncthreads();
  }
  if (t==0){
    float m=logits[0];
    #pragma unroll
    for (int c=1;c<10;++c) m=fmaxf(m,logits[c]);
    float ssum=0.f; float e[10];
    #pragma unroll
    for (int c=0;c<10;++c){ e[c]=expf(logits[c]-m); ssum+=e[c]; }
    #pragma unroll
    for (int c=0;c<10;++c) out[b*10+c]=e[c]/ssum;
  }
}

extern "C" void kernel_launch(void* const* d_in, const int* in_sizes, int n_in,
                              void* d_out, int out_size, void* d_ws, size_t ws_size,
                              hipStream_t stream){
  const float* x   = (const float*)d_in[0];
  const float* g0  = (const float*)d_in[1];
  const float* bt0 = (const float*)d_in[2];
  const float* W1  = (const float*)d_in[3];
  const float* b1  = (const float*)d_in[4];
  const float* W2  = (const float*)d_in[5];
  const float* b2  = (const float*)d_in[6];
  const float* g1  = (const float*)d_in[7];
  const float* bt1 = (const float*)d_in[8];
  const float* Wo  = (const float*)d_in[9];
  const float* bo  = (const float*)d_in[10];
  float* out = (float*)d_out;

  float* w     = (float*)d_ws;
  float* xs    = w;                   // BD
  float* xhi   = w + (size_t)BD;
  float* z     = w + (size_t)2*BD;
  float* sg    = w + (size_t)3*BD;
  float* kbuf  = w + (size_t)4*BD;    // 6*BD
  float* fpart = w + (size_t)10*BD;   // 16 slabs x (B*HID=2BD) = 32BD  (aliased)
  float* bpart = w + (size_t)10*BD;   // 32 slabs x BD = 32BD           (same region)
  float* coef  = w + (size_t)42*BD;   // 2BD
  float* prevE = w + (size_t)44*BD;   // BB
  float* scal  = prevE + 256;         // [dt, t]
  unsigned* err_bits = (unsigned*)(scal + 8);
  unsigned* rel_bits = err_bits + 1;
  int* flags = (int*)(err_bits + 2);  // [done, upd]
  unsigned* ctr1 = (unsigned*)(flags + 2);
  unsigned* ctr2 = ctr1 + 1;

  pool_ln<<<BB, BLK, 0, stream>>>(x, g0, bt0, xs, z, sg, scal, flags, prevE,
                                  err_bits, rel_bits, ctr1, ctr2);

  for (int step=0; step<16; ++step){
    for (int s=1; s<=6; ++s){
      fwd_mm<0><<<dim3(16,16), 256, 0, stream>>>(z, W1, fpart, flags);
      coef_fold<<<256, 256, 0, stream>>>(fpart, b1, W2, coef, flags);
      bwd_mm<<<dim3(8,32), 256, 0, stream>>>(coef, W1, bpart, flags);
      reduce_eval<<<512, BLK, 0, stream>>>(bpart, kbuf, xs, z, sg, xhi, scal,
                                           flags, err_bits, ctr1, s);
    }
    update_eval<<<512, BLK, 0, stream>>>(xs, xhi, z, sg, flags);
    fwd_mm<1><<<dim3(16,16), 256, 0, stream>>>(xs, W1, fpart, flags);
    reduce_E<<<BB, BLK, 0, stream>>>(fpart, b1, W2, b2, prevE, flags, rel_bits, scal, ctr2);
  }

  final_out<<<BB, BLK, 0, stream>>>(xs, g1, bt1, Wo, bo, out);
}

// Round 6
// 4005.371 us; speedup vs baseline: 3.2489x; 1.2679x over previous
//
#include <hip/hip_runtime.h>
#include <math.h>

#define BB 128
#define IMG 64
#define DD 1024
#define HID 2048
#define BD (BB*DD)
#define BLK 256
#define LP 72   // LDS pitch (bf16 elems): 144B rows -> 16B-group stride 9 (bank-clean)

#define DT0 0.1f
#define TOL_ 0.01f
#define MIN_DT_ 0.1f
#define MAX_DELTA_T_ 20.0f
#define REL_TOL_ 1e-3f
#define LN_EPS_ 1e-3f

typedef __attribute__((ext_vector_type(8))) short short8v;
typedef __attribute__((ext_vector_type(4))) float f32x4;

// RKF56 stage coefficients (a_ij), row = stage-1
__constant__ float RKA[6][5] = {
  {0.f,0.f,0.f,0.f,0.f},
  {0.25f,0.f,0.f,0.f,0.f},
  {(float)(3.0/32.0),(float)(9.0/32.0),0.f,0.f,0.f},
  {(float)(1932.0/2197.0),(float)(-7200.0/2197.0),(float)(7296.0/2197.0),0.f,0.f},
  {(float)(439.0/216.0),-8.0f,(float)(3680.0/513.0),(float)(-845.0/4104.0),0.f},
  {(float)(-8.0/27.0),2.0f,(float)(-3544.0/2565.0),(float)(1859.0/4104.0),(float)(-11.0/40.0)}
};

__device__ __forceinline__ void reflect(float x, float& zv, float& sv){
  int ii = (int)x;                 // trunc toward zero == astype(int32)
  bool odd = (ii & 1) != 0;
  zv = odd ? (1.0f - x) : x;
  sv = odd ? -1.0f : 1.0f;
}

// split x into bf16 hi + bf16 lo (hi+lo represents x to ~2^-18 relative)
__device__ __forceinline__ void split_bf16(float x, unsigned short& h, unsigned short& l){
  unsigned xb = __float_as_uint(x);
  unsigned hb = (xb + 0x8000u) & 0xFFFF0000u;
  h = (unsigned short)(hb >> 16);
  float r = x - __uint_as_float(hb);
  unsigned rb = __float_as_uint(r);
  l = (unsigned short)((rb + 0x8000u) >> 16);
}

// ---------------- one-time W1 prep: split + transposed split ----------------
__global__ __launch_bounds__(256)
void w1_split(const float* __restrict__ W1, unsigned short* __restrict__ W1h,
              unsigned short* __restrict__ W1l){
  size_t i = (size_t)blockIdx.x*256 + threadIdx.x;   // over D*HID/4
  float4 v = *(const float4*)&W1[i*4];
  unsigned short h0,l0,h1,l1,h2,l2,h3,l3;
  split_bf16(v.x,h0,l0); split_bf16(v.y,h1,l1);
  split_bf16(v.z,h2,l2); split_bf16(v.w,h3,l3);
  ushort4 hh = {h0,h1,h2,h3}, ll = {l0,l1,l2,l3};
  *(ushort4*)&W1h[i*4] = hh;
  *(ushort4*)&W1l[i*4] = ll;
}

__global__ __launch_bounds__(256)
void w1_trans(const float* __restrict__ W1, unsigned short* __restrict__ W1Th,
              unsigned short* __restrict__ W1Tl){
  __shared__ float tile[64][65];
  int d0 = blockIdx.x*64, j0 = blockIdx.y*64;
  int t = threadIdx.x;
  #pragma unroll
  for (int q=0;q<16;++q){
    int e = t + 256*q; int r = e>>6, c = e&63;
    tile[r][c] = W1[(size_t)(d0+r)*HID + j0 + c];
  }
  __syncthreads();
  #pragma unroll
  for (int q=0;q<16;++q){
    int e = t + 256*q; int r = e>>6, c = e&63;
    float x = tile[c][r];
    unsigned short h,l; split_bf16(x,h,l);
    W1Th[(size_t)(j0+r)*DD + d0 + c] = h;
    W1Tl[(size_t)(j0+r)*DD + d0 + c] = l;
  }
}

// ---------------- maxpool 2x2 + layernorm + state init ----------------
__global__ void pool_ln(const float* __restrict__ x, const float* __restrict__ g,
                        const float* __restrict__ bb, float* __restrict__ xs,
                        unsigned short* __restrict__ zh, unsigned short* __restrict__ zl,
                        float* __restrict__ sg,
                        float* __restrict__ scal, int* __restrict__ flags,
                        float* __restrict__ prevE, unsigned* err_bits, unsigned* rel_bits,
                        unsigned* ctr1, unsigned* ctr2){
  __shared__ float p[DD];
  __shared__ float red[BLK];
  int b = blockIdx.x, t = threadIdx.x;
  const float* xb = x + b*IMG*IMG;
  for (int idx=t; idx<DD; idx+=BLK){
    int r = idx>>5, c = idx&31;
    const float* base = xb + (r*2)*IMG + c*2;
    p[idx] = fmaxf(fmaxf(base[0], base[1]), fmaxf(base[IMG], base[IMG+1]));
  }
  __syncthreads();
  float s=0.f;
  for (int idx=t; idx<DD; idx+=BLK) s += p[idx];
  red[t]=s; __syncthreads();
  for (int st=BLK/2; st>0; st>>=1){ if (t<st) red[t]+=red[t+st]; __syncthreads(); }
  float mean = red[0]/(float)DD; __syncthreads();
  float v=0.f;
  for (int idx=t; idx<DD; idx+=BLK){ float d=p[idx]-mean; v+=d*d; }
  red[t]=v; __syncthreads();
  for (int st=BLK/2; st>0; st>>=1){ if (t<st) red[t]+=red[t+st]; __syncthreads(); }
  float var = red[0]/(float)DD;
  float inv = 1.0f/sqrtf(var + LN_EPS_);
  for (int idx=t; idx<DD; idx+=BLK){
    float val = (p[idx]-mean)*inv*g[idx] + bb[idx];
    xs[b*DD+idx] = val;
    float zv, sv; reflect(val, zv, sv);
    unsigned short h,l; split_bf16(zv,h,l);
    zh[b*DD+idx]=h; zl[b*DD+idx]=l; sg[b*DD+idx]=sv;
  }
  if (b==0){
    if (t==0){
      scal[0]=DT0; scal[1]=0.f; flags[0]=0; flags[1]=0;
      *err_bits=0u; *rel_bits=0u; *ctr1=0u; *ctr2=0u;
    }
    if (t<BB) prevE[t]=0.f;
  }
}

// ---------------- split-bf16 MFMA GEMM (partials, split-K) ----------------
// C_partial[128 x 128-tile] = A[128, kOff:kOff+64] @ B^T-ish[k, n]
// A: [m][k] row-major (pitchA), B stored as [n][k] row-major (pitchB).
// 3-term split product: hh + hl + lh. Output fp32 into slab blockIdx.y.
__global__ __launch_bounds__(256)
void mfma_mm(const unsigned short* __restrict__ Ah, const unsigned short* __restrict__ Al,
             int pitchA,
             const unsigned short* __restrict__ Bh, const unsigned short* __restrict__ Bl,
             int pitchB,
             float* __restrict__ outBase, int ldC, size_t slabStride,
             const int* __restrict__ flags, int guard_upd){
  if (flags[0]) return;
  if (guard_upd && !flags[1]) return;
  __shared__ unsigned short As[2][128][LP];
  __shared__ unsigned short Bs[2][128][LP];
  int n0 = blockIdx.x * 128;
  int kOff = blockIdx.y * 64;
  int t = threadIdx.x;
  #pragma unroll
  for (int q=0;q<4;++q){
    int e = t + 256*q;
    int m = e >> 3, kc = (e & 7) * 8;
    *(uint4*)&As[0][m][kc] = *(const uint4*)&Ah[(size_t)m*pitchA + kOff + kc];
    *(uint4*)&As[1][m][kc] = *(const uint4*)&Al[(size_t)m*pitchA + kOff + kc];
    *(uint4*)&Bs[0][m][kc] = *(const uint4*)&Bh[(size_t)(n0+m)*pitchB + kOff + kc];
    *(uint4*)&Bs[1][m][kc] = *(const uint4*)&Bl[(size_t)(n0+m)*pitchB + kOff + kc];
  }
  __syncthreads();
  int lane = t & 63, wave = t >> 6;
  int wm = (wave>>1)*64, wn = (wave&1)*64;
  int fr = lane & 15, kg = (lane>>4)*8;
  f32x4 acc[4][4];
  #pragma unroll
  for (int i=0;i<4;++i)
    #pragma unroll
    for (int j=0;j<4;++j)
      acc[i][j] = (f32x4){0.f,0.f,0.f,0.f};
  #pragma unroll
  for (int ks=0; ks<2; ++ks){
    short8v ah[4], al[4], bh[4], bl[4];
    #pragma unroll
    for (int f=0; f<4; ++f){
      ah[f] = *(const short8v*)&As[0][wm + f*16 + fr][kg + 32*ks];
      al[f] = *(const short8v*)&As[1][wm + f*16 + fr][kg + 32*ks];
      bh[f] = *(const short8v*)&Bs[0][wn + f*16 + fr][kg + 32*ks];
      bl[f] = *(const short8v*)&Bs[1][wn + f*16 + fr][kg + 32*ks];
    }
    #pragma unroll
    for (int i=0;i<4;++i)
      #pragma unroll
      for (int j=0;j<4;++j){
        acc[i][j] = __builtin_amdgcn_mfma_f32_16x16x32_bf16(ah[i], bh[j], acc[i][j], 0,0,0);
        acc[i][j] = __builtin_amdgcn_mfma_f32_16x16x32_bf16(ah[i], bl[j], acc[i][j], 0,0,0);
        acc[i][j] = __builtin_amdgcn_mfma_f32_16x16x32_bf16(al[i], bh[j], acc[i][j], 0,0,0);
      }
  }
  float* dst = outBase + (size_t)blockIdx.y * slabStride;
  int rbase = (lane>>4)*4;
  #pragma unroll
  for (int i=0;i<4;++i){
    #pragma unroll
    for (int j=0;j<4;++j){
      int col = n0 + wn + j*16 + fr;
      #pragma unroll
      for (int r=0;r<4;++r){
        int row = wm + i*16 + rbase + r;
        dst[(size_t)row*ldC + col] = acc[i][j][r];
      }
    }
  }
}

// ---------------- fold 16 fwd partials -> coef = mask(pre)*W2 (split bf16) --------
__global__ __launch_bounds__(256)
void coef_fold(const float* __restrict__ fpart, const float* __restrict__ b1,
               const float* __restrict__ W2,
               unsigned short* __restrict__ coefh, unsigned short* __restrict__ coefl,
               const int* __restrict__ flags){
  if (flags[0]) return;
  int i4 = blockIdx.x*256 + threadIdx.x;   // float4 index over B*HID/4 = 65536
  int j4 = (i4 & 511) * 4;
  float4 pre = *(const float4*)&b1[j4];
  #pragma unroll
  for (int c=0;c<16;++c){
    float4 v = *(const float4*)&fpart[(size_t)c*(BB*HID) + (size_t)i4*4];
    pre.x+=v.x; pre.y+=v.y; pre.z+=v.z; pre.w+=v.w;
  }
  float4 w2 = *(const float4*)&W2[j4];
  float o0 = pre.x>0.f ? w2.x : 0.f;
  float o1 = pre.y>0.f ? w2.y : 0.f;
  float o2 = pre.z>0.f ? w2.z : 0.f;
  float o3 = pre.w>0.f ? w2.w : 0.f;
  unsigned short h0,l0,h1,l1,h2,l2,h3,l3;
  split_bf16(o0,h0,l0); split_bf16(o1,h1,l1);
  split_bf16(o2,h2,l2); split_bf16(o3,h3,l3);
  ushort4 hh = {h0,h1,h2,h3}, ll = {l0,l1,l2,l3};
  *(ushort4*)&coefh[(size_t)i4*4] = hh;
  *(ushort4*)&coefl[(size_t)i4*4] = ll;
}

// ---------------- fold 32 bwd partials -> k_s; next eval point (or combine+err+scalar1) ----
__global__ void reduce_eval(const float* __restrict__ bpart, float* __restrict__ kbuf,
                            const float* __restrict__ xs,
                            unsigned short* __restrict__ zh, unsigned short* __restrict__ zl,
                            float* __restrict__ sg, float* __restrict__ xhi,
                            float* __restrict__ scal, int* __restrict__ flags,
                            unsigned* err_bits, unsigned* ctr1, int s){
  if (flags[0]) return;
  int idx = blockIdx.x*BLK + threadIdx.x;
  float sum = 0.f;
  #pragma unroll
  for (int c=0;c<32;++c) sum += bpart[(size_t)c*BD + idx];
  float ks = -sg[idx]*sum;
  kbuf[(size_t)(s-1)*BD + idx] = ks;
  float dt = scal[0];
  if (s < 6){
    float acc = RKA[s][s-1]*ks;
    for (int m=0;m<s-1;++m) acc += RKA[s][m]*kbuf[(size_t)m*BD+idx];
    float xe = xs[idx] + dt*acc;
    float zv, sv; reflect(xe, zv, sv);
    unsigned short h,l; split_bf16(zv,h,l);
    zh[idx]=h; zl[idx]=l; sg[idx]=sv;
  } else {
    __shared__ float red[BLK];
    float k1 = kbuf[idx], k3 = kbuf[2*(size_t)BD+idx], k4 = kbuf[3*(size_t)BD+idx],
          k5 = kbuf[4*(size_t)BD+idx];
    float k6 = ks;
    float x = xs[idx];
    float xlo = x + dt*((float)(25.0/216.0)*k1 + (float)(1408.0/2565.0)*k3
                      + (float)(2197.0/4104.0)*k4 - k5*0.2f);
    float xh  = x + dt*((float)(16.0/135.0)*k1 + (float)(6656.0/12825.0)*k3
                      + (float)(28561.0/56430.0)*k4 - (float)(9.0/50.0)*k5
                      + (float)(2.0/55.0)*k6);
    xhi[idx] = xh;
    float d = fabsf(xh - xlo);
    red[threadIdx.x]=d; __syncthreads();
    for (int st=BLK/2; st>0; st>>=1){
      if (threadIdx.x<st) red[threadIdx.x]=fmaxf(red[threadIdx.x],red[threadIdx.x+st]);
      __syncthreads();
    }
    if (threadIdx.x==0){
      atomicMax(err_bits, __float_as_uint(red[0]));
      __threadfence();
      unsigned tk = atomicAdd(ctr1, 1u);
      if (tk == 511u){                      // last of 512 blocks: scalar1
        *ctr1 = 0u;
        float err = __uint_as_float(atomicExch(err_bits, 0u));
        float dtc = scal[0];
        bool accept = (err <= TOL_) || (dtc <= MIN_DT_ + 1e-9f);
        flags[1] = accept ? 1 : 0;
        if (accept) scal[1] = scal[1] + dtc;
        float grow = 0.9f*dtc*powf(TOL_/(err+1e-12f), 0.2f);
        grow = fminf(fmaxf(grow, MIN_DT_), 1.0f);
        scal[0] = accept ? grow : fmaxf(dtc*0.5f, MIN_DT_);
      }
    }
  }
}

// ---------------- commit x (if accepted) + stage-1 eval point + xs split ----------------
__global__ void update_eval(float* __restrict__ xs, const float* __restrict__ xhi,
                            unsigned short* __restrict__ zh, unsigned short* __restrict__ zl,
                            float* __restrict__ sg,
                            unsigned short* __restrict__ xsh, unsigned short* __restrict__ xsl,
                            const int* __restrict__ flags){
  if (flags[0]) return;
  int idx = blockIdx.x*BLK + threadIdx.x;
  float x = flags[1] ? xhi[idx] : xs[idx];
  xs[idx] = x;
  float zv, sv; reflect(x, zv, sv);
  unsigned short h,l;
  split_bf16(zv,h,l); zh[idx]=h; zl[idx]=l; sg[idx]=sv;
  split_bf16(x,h,l);  xsh[idx]=h; xsl[idx]=l;
}

// ---------------- energy reduce: fold 16 fwd partials, relu*W2, row-sum; scalar2 ----------
__global__ void reduce_E(const float* __restrict__ fpart, const float* __restrict__ b1,
                         const float* __restrict__ W2, const float* __restrict__ b2,
                         float* __restrict__ prevE, int* __restrict__ flags,
                         unsigned* rel_bits, float* __restrict__ scal, unsigned* ctr2){
  if (flags[0] || !flags[1]) return;
  __shared__ float red[BLK];
  int b=blockIdx.x, t=threadIdx.x;
  float s=0.f;
  for (int j=t;j<HID;j+=BLK){
    float pre = b1[j];
    #pragma unroll
    for (int c=0;c<16;++c) pre += fpart[(size_t)c*(BB*HID) + (size_t)b*HID + j];
    s += fmaxf(pre,0.f)*W2[j];
  }
  red[t]=s; __syncthreads();
  for (int st=BLK/2; st>0; st>>=1){ if(t<st) red[t]+=red[t+st]; __syncthreads(); }
  if (t==0){
    float e = red[0] + b2[0];
    float pe = prevE[b];
    float r = fabsf(e-pe)/(fabsf(pe)+1e-8f);
    atomicMax(rel_bits, __float_as_uint(r));
    prevE[b]=e;
    __threadfence();
    unsigned tk = atomicAdd(ctr2, 1u);
    if (tk == 127u){                        // last of 128 blocks: scalar2
      *ctr2 = 0u;
      float tn = scal[1];
      float rel = __uint_as_float(atomicExch(rel_bits, 0u));
      if ((tn > MAX_DELTA_T_) || ((tn > 0.0f) && (rel < REL_TOL_))) flags[0]=1;
    }
  }
}

// ---------------- final: LN + linear(10) + softmax ----------------
__global__ void final_out(const float* __restrict__ xs, const float* __restrict__ g,
                          const float* __restrict__ bb, const float* __restrict__ Wo,
                          const float* __restrict__ bo, float* __restrict__ out){
  __shared__ float h[DD];
  __shared__ float red[BLK];
  __shared__ float logits[16];
  int b = blockIdx.x, t = threadIdx.x;
  float s=0.f;
  for (int i=t;i<DD;i+=BLK){ float v = xs[b*DD+i]; h[i]=v; s+=v; }
  red[t]=s; __syncthreads();
  for (int st=BLK/2; st>0; st>>=1){ if(t<st) red[t]+=red[t+st]; __syncthreads(); }
  float mean = red[0]/(float)DD; __syncthreads();
  float v2=0.f;
  for (int i=t;i<DD;i+=BLK){ float d=h[i]-mean; v2+=d*d; }
  red[t]=v2; __syncthreads();
  for (int st=BLK/2; st>0; st>>=1){ if(t<st) red[t]+=red[t+st]; __syncthreads(); }
  float var = red[0]/(float)DD; __syncthreads();
  float inv = 1.0f/sqrtf(var+LN_EPS_);
  float part[10];
  #pragma unroll
  for (int c=0;c<10;++c) part[c]=0.f;
  for (int i=t;i<DD;i+=BLK){
    float hn = (h[i]-mean)*inv*g[i] + bb[i];
    #pragma unroll
    for (int c=0;c<10;++c) part[c] += hn*Wo[i*10+c];
  }
  #pragma unroll
  for (int c=0;c<10;++c){
    red[t]=part[c]; __syncthreads();
    for (int st=BLK/2; st>0; st>>=1){ if(t<st) red[t]+=red[t+st]; __syncthreads(); }
    if (t==0) logits[c]=red[0]+bo[c];
    __syncthreads();
  }
  if (t==0){
    float m=logits[0];
    #pragma unroll
    for (int c=1;c<10;++c) m=fmaxf(m,logits[c]);
    float ssum=0.f; float e[10];
    #pragma unroll
    for (int c=0;c<10;++c){ e[c]=expf(logits[c]-m); ssum+=e[c]; }
    #pragma unroll
    for (int c=0;c<10;++c) out[b*10+c]=e[c]/ssum;
  }
}

extern "C" void kernel_launch(void* const* d_in, const int* in_sizes, int n_in,
                              void* d_out, int out_size, void* d_ws, size_t ws_size,
                              hipStream_t stream){
  const float* x   = (const float*)d_in[0];
  const float* g0  = (const float*)d_in[1];
  const float* bt0 = (const float*)d_in[2];
  const float* W1  = (const float*)d_in[3];
  const float* b1  = (const float*)d_in[4];
  const float* W2  = (const float*)d_in[5];
  const float* b2  = (const float*)d_in[6];
  const float* g1  = (const float*)d_in[7];
  const float* bt1 = (const float*)d_in[8];
  const float* Wo  = (const float*)d_in[9];
  const float* bo  = (const float*)d_in[10];
  float* out = (float*)d_out;

  char* w = (char*)d_ws;
  float* xs    = (float*)w;                         w += (size_t)BD*4;
  float* xhi   = (float*)w;                         w += (size_t)BD*4;
  float* sg    = (float*)w;                         w += (size_t)BD*4;
  float* kbuf  = (float*)w;                         w += (size_t)6*BD*4;
  float* fpart = (float*)w;                         // 16 x B*HID fp32 = 16 MB
  float* bpart = (float*)w;                         // 32 x BD fp32 (aliased)
  w += (size_t)16*BB*HID*4;
  unsigned short* zh    = (unsigned short*)w;       w += (size_t)BD*2;
  unsigned short* zl    = (unsigned short*)w;       w += (size_t)BD*2;
  unsigned short* xsh   = (unsigned short*)w;       w += (size_t)BD*2;
  unsigned short* xsl   = (unsigned short*)w;       w += (size_t)BD*2;
  unsigned short* coefh = (unsigned short*)w;       w += (size_t)BB*HID*2;
  unsigned short* coefl = (unsigned short*)w;       w += (size_t)BB*HID*2;
  unsigned short* W1h   = (unsigned short*)w;       w += (size_t)DD*HID*2;
  unsigned short* W1l   = (unsigned short*)w;       w += (size_t)DD*HID*2;
  unsigned short* W1Th  = (unsigned short*)w;       w += (size_t)DD*HID*2;
  unsigned short* W1Tl  = (unsigned short*)w;       w += (size_t)DD*HID*2;
  float* prevE = (float*)w;                         w += 256*4;
  float* scal  = (float*)w;                         w += 8*4;
  unsigned* err_bits = (unsigned*)w;                w += 4;
  unsigned* rel_bits = (unsigned*)w;                w += 4;
  int* flags = (int*)w;                             w += 2*4;
  unsigned* ctr1 = (unsigned*)w;                    w += 4;
  unsigned* ctr2 = (unsigned*)w;

  // one-time weight prep (re-done every call; deterministic, graph-safe)
  w1_split<<<(DD*HID/4)/256, 256, 0, stream>>>(W1, W1h, W1l);
  w1_trans<<<dim3(DD/64, HID/64), 256, 0, stream>>>(W1, W1Th, W1Tl);

  pool_ln<<<BB, BLK, 0, stream>>>(x, g0, bt0, xs, zh, zl, sg, scal, flags, prevE,
                                  err_bits, rel_bits, ctr1, ctr2);

  for (int step=0; step<16; ++step){
    for (int s=1; s<=6; ++s){
      // fwd: pre-partials = z @ W1  (A=z[B,D], B=W1T[n=j][k=d])
      mfma_mm<<<dim3(HID/128, DD/64), 256, 0, stream>>>(
          zh, zl, DD, W1Th, W1Tl, DD, fpart, HID, (size_t)BB*HID, flags, 0);
      coef_fold<<<256, 256, 0, stream>>>(fpart, b1, W2, coefh, coefl, flags);
      // bwd: k-partials = coef @ W1^T  (A=coef[B,HID], B=W1[n=i][k=j])
      mfma_mm<<<dim3(DD/128, HID/64), 256, 0, stream>>>(
          coefh, coefl, HID, W1h, W1l, HID, bpart, DD, (size_t)BD, flags, 0);
      reduce_eval<<<512, BLK, 0, stream>>>(bpart, kbuf, xs, zh, zl, sg, xhi, scal,
                                           flags, err_bits, ctr1, s);
    }
    update_eval<<<512, BLK, 0, stream>>>(xs, xhi, zh, zl, sg, xsh, xsl, flags);
    // energy eval on raw xs (guarded by upd flag)
    mfma_mm<<<dim3(HID/128, DD/64), 256, 0, stream>>>(
        xsh, xsl, DD, W1Th, W1Tl, DD, fpart, HID, (size_t)BB*HID, flags, 1);
    reduce_E<<<BB, BLK, 0, stream>>>(fpart, b1, W2, b2, prevE, flags, rel_bits, scal, ctr2);
  }

  final_out<<<BB, BLK, 0, stream>>>(xs, g1, bt1, Wo, bo, out);
}